// Round 27
// baseline (475.114 us; speedup 1.0000x reference)
//
#include <hip/hip_runtime.h>
#include <hip/hip_fp16.h>

// ---------------------------------------------------------------------------
// GAT 2-layer forward. Bucket-sorted CSR, slot-parallel alpha, hoisted
// denominator, 2-way-unrolled aggregation, transposed-W GEMM.
// Layer1: in=128, H=8, F=32.  Layer2: in=32, H=8, F=16.  N=1e5, E=1.6e6.
// r26 re-confirmed the 469us baseline on a healthy pod. This round re-lands
// the transposed-W GEMM (arithmetic-identical): wlds[c][k], row stride
// WS=KC+4=20 words (16B-aligned float4 rows, banks tiled) so the wv loads
// become 8x ds_read_b128 instead of 32x ds_read_b32 per 128 FMAs.
// (r20-r22 timeouts of this source coincided with the pod sick phase that
//  also killed the known-good baseline in r23-r25 — attributing to pod.)
// Softmax without max-subtraction (O(1) logits; validated r6-r26).
// ---------------------------------------------------------------------------

__device__ __forceinline__ float lrelu_exp(float v) {
    v = v > 0.f ? v : 0.2f * v;
    return __expf(v);
}

__global__ __launch_bounds__(256) void k_zero(float* __restrict__ p, int n) {
    int i = blockIdx.x * 256 + threadIdx.x;
    const int stride = gridDim.x * 256;
    for (; i < n; i += stride) p[i] = 0.f;
}

__global__ __launch_bounds__(256) void k_zero_int(int* __restrict__ p, int n) {
    int i = blockIdx.x * 256 + threadIdx.x;
    const int stride = gridDim.x * 256;
    for (; i < n; i += stride) p[i] = 0;
}

// ---------------- bucket-sort CSR build (main path) ----------------
__global__ __launch_bounds__(256) void k_bhist(const int* __restrict__ ei,
                                               int* __restrict__ gcnt,
                                               int E, int nblk, int nbkt) {
    __shared__ int cnt[256];
    const int t = threadIdx.x;
    cnt[t] = 0;
    __syncthreads();
    const int base = blockIdx.x * 4096;
#pragma unroll
    for (int i = 0; i < 16; ++i) {
        const int e = base + i * 256 + t;
        if (e < E) atomicAdd(&cnt[ei[E + e] >> 9], 1);
    }
    __syncthreads();
    if (t < nbkt) gcnt[t * nblk + blockIdx.x] = cnt[t];
}

__global__ __launch_bounds__(256) void k_scan_block2(int* __restrict__ g,
                                                     int* __restrict__ bsum, int L) {
    __shared__ int s[256];
    const int t = threadIdx.x;
    const int i = blockIdx.x * 256 + t;
    const int v = (i < L) ? g[i] : 0;
    s[t] = v;
    __syncthreads();
    for (int off = 1; off < 256; off <<= 1) {
        const int tv = (t >= off) ? s[t - off] : 0;
        __syncthreads();
        s[t] += tv;
        __syncthreads();
    }
    if (i < L) g[i] = s[t] - v;
    if (t == 255) bsum[blockIdx.x] = s[255];
}

__global__ __launch_bounds__(1024) void k_scan_sums(int* __restrict__ bsum, int NB) {
    __shared__ int s[1024];
    const int t = threadIdx.x;
    const int v = (t < NB) ? bsum[t] : 0;
    s[t] = v;
    __syncthreads();
    for (int off = 1; off < 1024; off <<= 1) {
        const int tv = (t >= off) ? s[t - off] : 0;
        __syncthreads();
        s[t] += tv;
        __syncthreads();
    }
    if (t < NB) bsum[t] = s[t] - v;
}

__global__ __launch_bounds__(256) void k_scan_add2(int* __restrict__ g,
                                                   const int* __restrict__ bsum, int L) {
    const int i = blockIdx.x * 256 + threadIdx.x;
    if (i < L) g[i] += bsum[blockIdx.x];
}

__global__ __launch_bounds__(256) void k_bucket_scatter(const int* __restrict__ ei,
                                                        const int* __restrict__ gbase,
                                                        int2* __restrict__ buf2,
                                                        int E, int nblk, int nbkt) {
    __shared__ int cnt[256];
    __shared__ int sbase[256];
    const int t = threadIdx.x;
    cnt[t] = 0;
    if (t < nbkt) sbase[t] = gbase[t * nblk + blockIdx.x];
    __syncthreads();
    const int base = blockIdx.x * 4096;
#pragma unroll
    for (int i = 0; i < 16; ++i) {
        const int e = base + i * 256 + t;
        if (e < E) {
            const int src = ei[e];
            const int dst = ei[E + e];
            const int b = dst >> 9;
            const int r = atomicAdd(&cnt[b], 1);
            buf2[sbase[b] + r] = make_int2(src, dst);
        }
    }
}

__global__ __launch_bounds__(256) void k_bucket_csr(const int2* __restrict__ buf2,
                                                    const int* __restrict__ gbase,
                                                    int* __restrict__ rowptr,
                                                    int* __restrict__ esrc,
                                                    int* __restrict__ sdst,
                                                    int N, int E, int nblk, int nbkt) {
    __shared__ int hist[512], curs[512], ps[256];
    __shared__ int sh_base, sh_end;
    const int t = threadIdx.x;
    const int b = blockIdx.x;
    const int node0 = b << 9;
    if (t == 0) {
        sh_base = gbase[b * nblk];
        sh_end  = (b + 1 < nbkt) ? gbase[(b + 1) * nblk] : E;
        if (b == 0) rowptr[N] = E;
    }
    hist[t] = 0;
    hist[t + 256] = 0;
    __syncthreads();
    const int eb = sh_base, ee = sh_end;
    for (int e = eb + t; e < ee; e += 256)
        atomicAdd(&hist[buf2[e].y - node0], 1);
    __syncthreads();
    const int p0 = hist[2 * t], p1 = hist[2 * t + 1];
    const int pr = p0 + p1;
    ps[t] = pr;
    __syncthreads();
    for (int off = 1; off < 256; off <<= 1) {
        const int v = (t >= off) ? ps[t - off] : 0;
        __syncthreads();
        ps[t] += v;
        __syncthreads();
    }
    const int e0 = ps[t] - pr;
    curs[2 * t]     = e0;
    curs[2 * t + 1] = e0 + p0;
    const int nn = min(512, N - node0);
    if (2 * t < nn)     rowptr[node0 + 2 * t]     = eb + e0;
    if (2 * t + 1 < nn) rowptr[node0 + 2 * t + 1] = eb + e0 + p0;
    __syncthreads();
    for (int e = eb + t; e < ee; e += 256) {
        const int2 r = buf2[e];
        const int rk = atomicAdd(&curs[r.y - node0], 1);
        esrc[eb + rk] = r.x;
        sdst[eb + rk] = r.y;
    }
}

// ---------------- legacy CSR build (fallback path only) ----------------
__global__ __launch_bounds__(256) void k_hist(const int* __restrict__ ei,
                                              int* __restrict__ deg, int E) {
    const int e = blockIdx.x * 256 + threadIdx.x;
    if (e < E) atomicAdd(&deg[ei[E + e]], 1);
}

__global__ __launch_bounds__(256) void k_scan_block(const int* __restrict__ deg,
                                                    int* __restrict__ rowptr,
                                                    int* __restrict__ bsum, int N) {
    __shared__ int s[256];
    const int t = threadIdx.x;
    const int i = blockIdx.x * 256 + t;
    const int v = (i < N) ? deg[i] : 0;
    s[t] = v;
    __syncthreads();
    for (int off = 1; off < 256; off <<= 1) {
        const int tv = (t >= off) ? s[t - off] : 0;
        __syncthreads();
        s[t] += tv;
        __syncthreads();
    }
    if (i < N) rowptr[i] = s[t] - v;
    if (t == 255) bsum[blockIdx.x] = s[255];
}

__global__ __launch_bounds__(256) void k_scan_add(int* __restrict__ rowptr,
                                                  const int* __restrict__ bsum,
                                                  int* __restrict__ cursor, int N, int E) {
    const int i = blockIdx.x * 256 + threadIdx.x;
    if (i < N) {
        const int r = rowptr[i] + bsum[blockIdx.x];
        rowptr[i] = r;
        cursor[i] = r;
    }
    if (i == 0) rowptr[N] = E;
}

__global__ __launch_bounds__(256) void k_scatter(const int* __restrict__ ei,
                                                 int* __restrict__ cursor,
                                                 int* __restrict__ esrc, int E) {
    const int e = blockIdx.x * 256 + threadIdx.x;
    if (e >= E) return;
    const int src = ei[e];
    const int dst = ei[E + e];
    const int pos = atomicAdd(&cursor[dst], 1);
    esrc[pos] = src;
}

// ---------------- main-path GEMM: 4x8 tile, W transposed in LDS -------------
// wlds[c][k], row stride WS=KC+4=20 words: float4 rows stay 16B-aligned and
// 20*c mod 32 tiles the banks. wv = 8x ds_read_b128 (was 32x b32).
template <int IN, int C, int F>
__global__ __launch_bounds__(256) void k_gemm_big(const float* __restrict__ x,
                                                  const float* __restrict__ W,
                                                  __half* __restrict__ h, int N) {
    constexpr int CJ = C / 32;
    constexpr int KC = 16;
    constexpr int WS = KC + 4;  // 20 words: 16B-aligned rows, bank-tiling
    __shared__ float xs[32 * IN];
    __shared__ float wlds[C * WS];
    const int t  = threadIdx.x;
    const int n0 = blockIdx.x * 32;

    const float4* src4 = (const float4*)(x + (size_t)n0 * IN);
    float4* xs4 = (float4*)xs;
    constexpr int NV = 32 * IN / 4;
    for (int idx = t; idx < NV; idx += 256) {
        const int row = idx / (IN / 4);
        xs4[idx] = (n0 + row < N) ? src4[idx] : make_float4(0.f, 0.f, 0.f, 0.f);
    }

    const int tc = t & 31;
    const int tr = t >> 5;
    float acc[4][CJ];
#pragma unroll
    for (int i = 0; i < 4; ++i)
#pragma unroll
        for (int j = 0; j < CJ; ++j) acc[i][j] = 0.f;

#pragma unroll 1
    for (int kc = 0; kc < IN; kc += KC) {
        __syncthreads();
        for (int idx = t; idx < KC * C; idx += 256) {
            const int k = idx / C, c = idx % C;
            wlds[c * WS + k] = W[(size_t)(kc + k) * C + c];
        }
        __syncthreads();
#pragma unroll 1
        for (int q = 0; q < KC / 4; ++q) {
            float4 xv[4];
#pragma unroll
            for (int i = 0; i < 4; ++i)
                xv[i] = *(const float4*)&xs[(tr * 4 + i) * IN + kc + q * 4];
            float4 wv4[CJ];
#pragma unroll
            for (int j = 0; j < CJ; ++j)
                wv4[j] = *(const float4*)&wlds[(tc + j * 32) * WS + q * 4];
#pragma unroll
            for (int kk = 0; kk < 4; ++kk) {
#pragma unroll
                for (int i = 0; i < 4; ++i) {
                    const float xvv = ((const float*)&xv[i])[kk];
#pragma unroll
                    for (int j = 0; j < CJ; ++j)
                        acc[i][j] = fmaf(xvv, ((const float*)&wv4[j])[kk], acc[i][j]);
                }
            }
        }
    }

    if constexpr (C == 256 && F == 32) {
#pragma unroll
        for (int i = 0; i < 4; ++i) {
            const int r = n0 + tr * 4 + i;
            if (r < N) {
                __half tmp[8];
#pragma unroll
                for (int j = 0; j < 8; ++j) tmp[j] = __float2half(acc[i][j]);
                *(float4*)(h + (size_t)r * 256 + tc * 8) = *(const float4*)tmp;
            }
        }
    } else {
#pragma unroll
        for (int i = 0; i < 4; ++i) {
            const int r = n0 + tr * 4 + i;
            if (r < N) {
#pragma unroll
                for (int j = 0; j < CJ; ++j) {
                    const int c = tc + j * 32;
                    h[(size_t)r * C + (c % F) * 8 + (c / F)] = __float2half(acc[i][j]);
                }
            }
        }
    }
}

// Attention dots from fp16 h [N, F, HG]; writes a_s/a_d [N,8] at head hb+hl.
template <int F, int HG>
__global__ __launch_bounds__(256) void k_dots_h(const __half* __restrict__ h,
                                                const float* __restrict__ atts,
                                                const float* __restrict__ attd,
                                                float* __restrict__ as_,
                                                float* __restrict__ ad_, int N, int hb) {
    const int i = blockIdx.x * 256 + threadIdx.x;
    if (i >= N * HG) return;
    const int n  = i / HG;
    const int hl = i % HG;
    const int hg = hb + hl;
    const __half* hp = h + (size_t)n * (F * HG) + hl;
    const float* sv = atts + hg * F;
    const float* dv = attd + hg * F;
    float s = 0.f, d = 0.f;
#pragma unroll
    for (int f = 0; f < F; ++f) {
        const float v = __half2float(hp[f * HG]);
        s = fmaf(v, sv[f], s);
        d = fmaf(v, dv[f], d);
    }
    as_[(size_t)n * 8 + hg] = s;
    ad_[(size_t)n * 8 + hg] = d;
}

// Slot-parallel alpha: coalesced esrc/sdst reads, L2 gathers, coalesced store.
__global__ __launch_bounds__(256) void k_alpha_csr(const int* __restrict__ esrc,
                                                   const int* __restrict__ sdst,
                                                   const float* __restrict__ as_,
                                                   const float* __restrict__ ad_,
                                                   __half* __restrict__ exbuf, int E) {
    const int p = blockIdx.x * 256 + threadIdx.x;
    if (p >= E) return;
    const int src = esrc[p];
    const int dst = sdst[p];
    const float4 s0 = *(const float4*)(as_ + (size_t)src * 8);
    const float4 s1 = *(const float4*)(as_ + (size_t)src * 8 + 4);
    const float4 d0 = *(const float4*)(ad_ + (size_t)dst * 8);
    const float4 d1 = *(const float4*)(ad_ + (size_t)dst * 8 + 4);
    __half tmp[8];
    tmp[0] = __float2half(lrelu_exp(s0.x + d0.x));
    tmp[1] = __float2half(lrelu_exp(s0.y + d0.y));
    tmp[2] = __float2half(lrelu_exp(s0.z + d0.z));
    tmp[3] = __float2half(lrelu_exp(s0.w + d0.w));
    tmp[4] = __float2half(lrelu_exp(s1.x + d1.x));
    tmp[5] = __float2half(lrelu_exp(s1.y + d1.y));
    tmp[6] = __float2half(lrelu_exp(s1.z + d1.z));
    tmp[7] = __float2half(lrelu_exp(s1.w + d1.w));
    *(float4*)(exbuf + (size_t)p * 8) = *(const float4*)tmp;
}

// Per-(node,head) denominator from CONTIGUOUS exbuf CSR rows.
__global__ __launch_bounds__(256) void k_rinv(const int* __restrict__ rowptr,
                                              const __half* __restrict__ exbuf,
                                              float* __restrict__ rinv, int N) {
    const int i = blockIdx.x * 256 + threadIdx.x;
    if (i >= N * 8) return;
    const int n  = i >> 3;
    const int hh = i & 7;
    const int r0 = rowptr[n], r1 = rowptr[n + 1];
    float den = 0.f;
    for (int e = r0; e < r1; ++e)
        den += __half2float(exbuf[(size_t)e * 8 + hh]);
    rinv[i] = 1.f / (den + 1e-16f);
}

// Aggregation: 2-way edge unroll, dual accumulators, rinv applied at end.
template <int F, int MODE>
__global__ __launch_bounds__(256) void k_agg_ex3(const int* __restrict__ rowptr,
                                                 const int* __restrict__ esrc,
                                                 const __half* __restrict__ exbuf,
                                                 const float* __restrict__ rinv,
                                                 const __half* __restrict__ h,
                                                 const float* __restrict__ bias,
                                                 float* __restrict__ outp, int N) {
    constexpr int NPB = 256 / F;
    const int n = blockIdx.x * NPB + threadIdx.x / F;
    const int f = threadIdx.x % F;
    if (n >= N) return;
    const int r0 = rowptr[n], r1 = rowptr[n + 1];

    float accA[8], accB[8];
#pragma unroll
    for (int k = 0; k < 8; ++k) { accA[k] = 0.f; accB[k] = 0.f; }

    int e = r0;
    for (; e + 2 <= r1; e += 2) {
        const int s0 = esrc[e];
        const int s1 = esrc[e + 1];
        const float4 ex0 = *(const float4*)(exbuf + (size_t)e * 8);
        const float4 ex1 = *(const float4*)(exbuf + (size_t)(e + 1) * 8);
        const float4 h0  = *(const float4*)(h + (size_t)s0 * (F * 8) + f * 8);
        const float4 h1  = *(const float4*)(h + (size_t)s1 * (F * 8) + f * 8);
        const __half2* e20 = (const __half2*)&ex0;
        const __half2* h20 = (const __half2*)&h0;
        const __half2* e21 = (const __half2*)&ex1;
        const __half2* h21 = (const __half2*)&h1;
#pragma unroll
        for (int k = 0; k < 4; ++k) {
            const float2 ef0 = __half22float2(e20[k]);
            const float2 hf0 = __half22float2(h20[k]);
            accA[2 * k]     = fmaf(ef0.x, hf0.x, accA[2 * k]);
            accA[2 * k + 1] = fmaf(ef0.y, hf0.y, accA[2 * k + 1]);
            const float2 ef1 = __half22float2(e21[k]);
            const float2 hf1 = __half22float2(h21[k]);
            accB[2 * k]     = fmaf(ef1.x, hf1.x, accB[2 * k]);
            accB[2 * k + 1] = fmaf(ef1.y, hf1.y, accB[2 * k + 1]);
        }
    }
    if (e < r1) {
        const int s0 = esrc[e];
        const float4 ex0 = *(const float4*)(exbuf + (size_t)e * 8);
        const float4 h0  = *(const float4*)(h + (size_t)s0 * (F * 8) + f * 8);
        const __half2* e20 = (const __half2*)&ex0;
        const __half2* h20 = (const __half2*)&h0;
#pragma unroll
        for (int k = 0; k < 4; ++k) {
            const float2 ef0 = __half22float2(e20[k]);
            const float2 hf0 = __half22float2(h20[k]);
            accA[2 * k]     = fmaf(ef0.x, hf0.x, accA[2 * k]);
            accA[2 * k + 1] = fmaf(ef0.y, hf0.y, accA[2 * k + 1]);
        }
    }
    const float* rv = rinv + (size_t)n * 8;
    float s = 0.f;
#pragma unroll
    for (int k = 0; k < 8; ++k) s += (accA[k] + accB[k]) * rv[k];
    float v = 0.125f * s + bias[f];
    if constexpr (MODE == 1) v = v > 0.f ? v : 0.f;
    outp[(size_t)n * F + f] = v;
}

// ---------------- fallback path (r8-proven) ----------------
template <int IN, int C, int OW, int F>
__global__ __launch_bounds__(256) void k_gemm_h(const float* __restrict__ x,
                                                const float* __restrict__ W,
                                                __half* __restrict__ h, int N, int c0) {
    constexpr int HG = C / F;
    __shared__ float xs[32 * IN];
    const int t  = threadIdx.x;
    const int n0 = blockIdx.x * 32;
    const float4* src4 = (const float4*)(x + (size_t)n0 * IN);
    float4* xs4 = (float4*)xs;
    constexpr int NV = 32 * IN / 4;
    for (int idx = t; idx < NV; idx += 256) {
        const int row = idx / (IN / 4);
        xs4[idx] = (n0 + row < N) ? src4[idx] : make_float4(0.f, 0.f, 0.f, 0.f);
    }
    __syncthreads();
    const int idx = t % C;
    const int r0  = t / C;
    constexpr int RSTEP = 256 / C;
    constexpr int RPT   = 32 / RSTEP;
    const int f  = idx / HG;
    const int hd = idx % HG;
    float acc[RPT];
#pragma unroll
    for (int i = 0; i < RPT; ++i) acc[i] = 0.f;
    const float* Wc = W + c0 + hd * F + f;
#pragma unroll 1
    for (int k = 0; k < IN; k += 4) {
        const float w0 = Wc[(k + 0) * OW];
        const float w1 = Wc[(k + 1) * OW];
        const float w2 = Wc[(k + 2) * OW];
        const float w3 = Wc[(k + 3) * OW];
#pragma unroll
        for (int i = 0; i < RPT; ++i) {
            const int r = r0 + i * RSTEP;
            const float4 xv = *(const float4*)&xs[r * IN + k];
            acc[i] = fmaf(xv.x, w0, fmaf(xv.y, w1, fmaf(xv.z, w2, fmaf(xv.w, w3, acc[i]))));
        }
    }
#pragma unroll
    for (int i = 0; i < RPT; ++i) {
        const int r = r0 + i * RSTEP;
        if (n0 + r < N) h[(size_t)(n0 + r) * C + idx] = __float2half(acc[i]);
    }
}

template <int HG>
__global__ __launch_bounds__(256) void k_denom(const int* __restrict__ rowptr,
                                               const int* __restrict__ esrc,
                                               const float* __restrict__ as_,
                                               const float* __restrict__ ad_,
                                               float* __restrict__ rinv, int N, int hb) {
    const int i = blockIdx.x * 256 + threadIdx.x;
    if (i >= N * HG) return;
    const int n  = i / HG;
    const int hl = i % HG;
    const float ad = ad_[(size_t)n * 8 + hb + hl];
    const int r0 = rowptr[n];
    const int r1 = rowptr[n + 1];
    float s = 0.f;
    for (int e = r0; e < r1; ++e)
        s += lrelu_exp(as_[(size_t)esrc[e] * 8 + hb + hl] + ad);
    rinv[(size_t)n * 8 + hb + hl] = 1.f / (s + 1e-16f);
}

template <int F, int HG>
__global__ __launch_bounds__(256) void k_csr_agg_hg(const int* __restrict__ rowptr,
                                                    const int* __restrict__ esrc,
                                                    const float* __restrict__ as_,
                                                    const float* __restrict__ ad_,
                                                    const float* __restrict__ rinv,
                                                    const __half* __restrict__ h,
                                                    float* __restrict__ outp,
                                                    int N, int hb) {
    constexpr int NPB = 256 / F;
    const int n = blockIdx.x * NPB + threadIdx.x / F;
    const int f = threadIdx.x % F;
    if (n >= N) return;
    const int r0 = rowptr[n];
    const int r1 = rowptr[n + 1];
    float ad[HG], rv[HG];
#pragma unroll
    for (int k = 0; k < HG; ++k) {
        ad[k] = ad_[(size_t)n * 8 + hb + k];
        rv[k] = rinv[(size_t)n * 8 + hb + k];
    }
    float a0 = 0.f;
    for (int e = r0; e < r1; ++e) {
        const int src = esrc[e];
        const float* sp = as_ + (size_t)src * 8 + hb;
        const __half* hp = h + (size_t)src * (F * HG) + f * HG;
#pragma unroll
        for (int k = 0; k < HG; ++k) {
            const float al = lrelu_exp(sp[k] + ad[k]) * rv[k];
            a0 = fmaf(al, __half2float(hp[k]), a0);
        }
    }
    outp[(size_t)n * F + f] += 0.125f * a0;
}

__global__ __launch_bounds__(256) void k_relu_bias(float* __restrict__ a,
                                                   const float* __restrict__ b, int total) {
    const int i = blockIdx.x * 256 + threadIdx.x;
    if (i < total) {
        const float v = a[i] + b[i & 31];
        a[i] = v > 0.f ? v : 0.f;
    }
}

__global__ __launch_bounds__(256) void k_bias_inplace(float* __restrict__ a,
                                                      const float* __restrict__ b, int total) {
    const int i = blockIdx.x * 256 + threadIdx.x;
    if (i < total) a[i] += b[i & 15];
}

// ---------------- drivers ----------------
static void run_full(const float* x, const int* ei,
                     const float* W1, const float* as1, const float* ad1, const float* b1,
                     const float* W2, const float* as2, const float* ad2, const float* b2,
                     float* out, int N, int E, char* ws, hipStream_t stream) {
    auto align256 = [](size_t b) { return (b + 255) & ~(size_t)255; };
    size_t off = 0;
    auto alloc = [&](size_t bytes) { char* p = ws + off; off += align256(bytes); return p; };

    const int NBLKC = (E + 4095) / 4096;
    const int nbkt  = (N + 511) >> 9;
    const int L     = nbkt * NBLKC;

    __half* hbuf  = (__half*)alloc((size_t)N * 256 * 2);
    __half* exbuf = (__half*)alloc((size_t)E * 8 * 2);
    float* a_s    = (float*)alloc((size_t)N * 8 * 4);
    float* a_d    = (float*)alloc((size_t)N * 8 * 4);
    float* rinv   = (float*)alloc((size_t)N * 8 * 4);
    size_t acc_bytes = (size_t)N * 32 * 4;
    size_t buf2_bytes = (size_t)E * 8;
    float* acc1   = (float*)alloc(acc_bytes > buf2_bytes ? acc_bytes : buf2_bytes);
    int2* buf2    = (int2*)acc1;            // aliased: buf2 dead before agg1 writes acc1
    int* rowptr   = (int*)alloc((size_t)(N + 1) * 4);
    int* esrc     = (int*)alloc((size_t)E * 4);
    int* sdst     = (int*)alloc((size_t)E * 4);
    int* gcnt     = (int*)alloc((size_t)L * 4);
    int* bsum2    = (int*)alloc(1024 * 4);

    // ---- bucket-sort CSR build ----
    const int NBs = (L + 255) / 256;
    k_bhist<<<NBLKC, 256, 0, stream>>>(ei, gcnt, E, NBLKC, nbkt);
    k_scan_block2<<<NBs, 256, 0, stream>>>(gcnt, bsum2, L);
    k_scan_sums<<<1, 1024, 0, stream>>>(bsum2, NBs);
    k_scan_add2<<<NBs, 256, 0, stream>>>(gcnt, bsum2, L);
    k_bucket_scatter<<<NBLKC, 256, 0, stream>>>(ei, gcnt, buf2, E, NBLKC, nbkt);
    k_bucket_csr<<<nbkt, 256, 0, stream>>>(buf2, gcnt, rowptr, esrc, sdst, N, E, NBLKC, nbkt);

    const int NBg = (N + 31) / 32;
    const int nbp = (N * 8 + 255) / 256;
    const int NBe = (E + 255) / 256;
    // layer 1
    k_gemm_big<128, 256, 32><<<NBg, 256, 0, stream>>>(x, W1, hbuf, N);
    k_dots_h<32, 8><<<nbp, 256, 0, stream>>>(hbuf, as1, ad1, a_s, a_d, N, 0);
    k_alpha_csr<<<NBe, 256, 0, stream>>>(esrc, sdst, a_s, a_d, exbuf, E);
    k_rinv<<<nbp, 256, 0, stream>>>(rowptr, exbuf, rinv, N);
    k_agg_ex3<32, 1><<<(N + 7) / 8, 256, 0, stream>>>(rowptr, esrc, exbuf, rinv, hbuf, b1, acc1, N);
    // layer 2
    k_gemm_big<32, 128, 16><<<NBg, 256, 0, stream>>>(acc1, W2, hbuf, N);
    k_dots_h<16, 8><<<nbp, 256, 0, stream>>>(hbuf, as2, ad2, a_s, a_d, N, 0);
    k_alpha_csr<<<NBe, 256, 0, stream>>>(esrc, sdst, a_s, a_d, exbuf, E);
    k_rinv<<<nbp, 256, 0, stream>>>(rowptr, exbuf, rinv, N);
    k_agg_ex3<16, 2><<<(N + 15) / 16, 256, 0, stream>>>(rowptr, esrc, exbuf, rinv, hbuf, b2, out, N);
}

static void run_fallback4(const float* x, const int* ei,
                          const float* W1, const float* as1, const float* ad1, const float* b1,
                          const float* W2, const float* as2, const float* ad2, const float* b2,
                          float* out, int N, int E, char* ws, hipStream_t stream) {
    constexpr int HG = 4;
    auto align256 = [](size_t b) { return (b + 255) & ~(size_t)255; };
    size_t off = 0;
    auto alloc = [&](size_t bytes) { char* p = ws + off; off += align256(bytes); return p; };

    __half* hbuf = (__half*)alloc((size_t)N * HG * 32 * 2);
    float* a_s   = (float*)alloc((size_t)N * 8 * 4);
    float* a_d   = (float*)alloc((size_t)N * 8 * 4);
    float* rinv  = (float*)alloc((size_t)N * 8 * 4);
    float* acc1  = (float*)alloc((size_t)N * 32 * 4);
    int* rowptr  = (int*)alloc((size_t)(N + 1) * 4);
    int* cursor  = (int*)alloc((size_t)N * 4);
    int* deg     = (int*)alloc((size_t)N * 4);
    int* bsum    = (int*)alloc(1024 * 4);
    int* esrc    = (int*)alloc((size_t)E * 4);

    const int NBn = (N + 255) / 256;
    const int NBe = (E + 255) / 256;
    k_zero_int<<<512, 256, 0, stream>>>(deg, N);
    k_hist<<<NBe, 256, 0, stream>>>(ei, deg, E);
    k_scan_block<<<NBn, 256, 0, stream>>>(deg, rowptr, bsum, N);
    k_scan_sums<<<1, 1024, 0, stream>>>(bsum, NBn);
    k_scan_add<<<NBn, 256, 0, stream>>>(rowptr, bsum, cursor, N, E);
    k_scatter<<<NBe, 256, 0, stream>>>(ei, cursor, esrc, E);

    k_zero<<<512, 256, 0, stream>>>(acc1, N * 32);
    k_zero<<<512, 256, 0, stream>>>(out, N * 16);

    const int nbp = (N * HG + 255) / 256;
    for (int g = 0; g < 2; ++g) {
        k_gemm_h<128, 128, 256, 32><<<NBn * 8, 256, 0, stream>>>(x, W1, hbuf, N, g * 128);
        k_dots_h<32, HG><<<nbp, 256, 0, stream>>>(hbuf, as1, ad1, a_s, a_d, N, g * HG);
        k_denom<HG><<<nbp, 256, 0, stream>>>(rowptr, esrc, a_s, a_d, rinv, N, g * HG);
        k_csr_agg_hg<32, HG><<<(N + 7) / 8, 256, 0, stream>>>(rowptr, esrc, a_s, a_d, rinv,
                                                              hbuf, acc1, N, g * HG);
    }
    k_relu_bias<<<(N * 32 + 255) / 256, 256, 0, stream>>>(acc1, b1, N * 32);

    for (int g = 0; g < 2; ++g) {
        k_gemm_h<32, 64, 128, 16><<<NBn * 8, 256, 0, stream>>>(acc1, W2, hbuf, N, g * 64);
        k_dots_h<16, HG><<<nbp, 256, 0, stream>>>(hbuf, as2, ad2, a_s, a_d, N, g * HG);
        k_denom<HG><<<nbp, 256, 0, stream>>>(rowptr, esrc, a_s, a_d, rinv, N, g * HG);
        k_csr_agg_hg<16, HG><<<(N + 15) / 16, 256, 0, stream>>>(rowptr, esrc, a_s, a_d, rinv,
                                                                hbuf, out, N, g * HG);
    }
    k_bias_inplace<<<(N * 16 + 255) / 256, 256, 0, stream>>>(out, b2, N * 16);
}

extern "C" void kernel_launch(void* const* d_in, const int* in_sizes, int n_in,
                              void* d_out, int out_size, void* d_ws, size_t ws_size,
                              hipStream_t stream) {
    const float* x   = (const float*)d_in[0];
    const int*   ei  = (const int*)d_in[1];
    const float* W1  = (const float*)d_in[2];
    const float* as1 = (const float*)d_in[3];
    const float* ad1 = (const float*)d_in[4];
    const float* b1  = (const float*)d_in[5];
    const float* W2  = (const float*)d_in[6];
    const float* as2 = (const float*)d_in[7];
    const float* ad2 = (const float*)d_in[8];
    const float* b2  = (const float*)d_in[9];
    float* out = (float*)d_out;

    const int N = in_sizes[0] / 128;
    const int E = in_sizes[1] / 2;

    const int NBLKC = (E + 4095) / 4096;
    const int nbkt  = (N + 511) >> 9;
    const int L     = nbkt * NBLKC;
    const size_t acc_or_buf2 = ((size_t)N * 32 * 4 > (size_t)E * 8) ? (size_t)N * 32 * 4
                                                                    : (size_t)E * 8;
    const size_t need_full = (size_t)2 * N * 256 + (size_t)2 * E * 8 +
                             (size_t)4 * N * 24 + acc_or_buf2 +
                             (size_t)4 * (N + 1) + (size_t)8 * E +
                             (size_t)4 * L + 4096 + 20 * 256;
    char* ws = (char*)d_ws;
    if (ws_size >= need_full && nbkt <= 256 && (L + 255) / 256 <= 1024) {
        run_full(x, ei, W1, as1, ad1, b1, W2, as2, ad2, b2, out, N, E, ws, stream);
    } else {
        run_fallback4(x, ei, W1, as1, ad1, b1, W2, as2, ad2, b2, out, N, E, ws, stream);
    }
}

// Round 28
// 394.442 us; speedup vs baseline: 1.2045x; 1.2045x over previous
//
#include <hip/hip_runtime.h>
#include <hip/hip_fp16.h>

// ---------------------------------------------------------------------------
// GAT 2-layer forward. Bucket-sorted CSR, slot-parallel alpha, hoisted
// denominator, 2-way-unrolled aggregation. Layer-1 GEMM on MFMA fp16.
// Layer1: in=128, H=8, F=32.  Layer2: in=32, H=8, F=16.  N=1e5, E=1.6e6.
// r27: transposed-W GEMM neutral (475 vs 469) -> LDS-issue theory falsified.
// This round: layer-1 GEMM via mfma_f32_16x16x32_f16. Fragment-layout risk
// eliminated by loading A and B with the SAME (slot,group)->k bijection
// (k-permutation cancels in the dot product); m/n lane mapping and C/D
// layout (col=lane&15,row=(lane>>4)*4+reg) are HW-verified. W pre-transposed
// +fp16 once (k_prep_w). Layer-2 GEMM stays exact fp32 (r18-proven).
// Softmax without max-subtraction (O(1) logits; validated r6-r27).
// ---------------------------------------------------------------------------

typedef _Float16 f16x8 __attribute__((ext_vector_type(8)));
typedef float f32x4 __attribute__((ext_vector_type(4)));

__device__ __forceinline__ float lrelu_exp(float v) {
    v = v > 0.f ? v : 0.2f * v;
    return __expf(v);
}

__global__ __launch_bounds__(256) void k_zero(float* __restrict__ p, int n) {
    int i = blockIdx.x * 256 + threadIdx.x;
    const int stride = gridDim.x * 256;
    for (; i < n; i += stride) p[i] = 0.f;
}

__global__ __launch_bounds__(256) void k_zero_int(int* __restrict__ p, int n) {
    int i = blockIdx.x * 256 + threadIdx.x;
    const int stride = gridDim.x * 256;
    for (; i < n; i += stride) p[i] = 0;
}

// ---------------- bucket-sort CSR build (main path) ----------------
__global__ __launch_bounds__(256) void k_bhist(const int* __restrict__ ei,
                                               int* __restrict__ gcnt,
                                               int E, int nblk, int nbkt) {
    __shared__ int cnt[256];
    const int t = threadIdx.x;
    cnt[t] = 0;
    __syncthreads();
    const int base = blockIdx.x * 4096;
#pragma unroll
    for (int i = 0; i < 16; ++i) {
        const int e = base + i * 256 + t;
        if (e < E) atomicAdd(&cnt[ei[E + e] >> 9], 1);
    }
    __syncthreads();
    if (t < nbkt) gcnt[t * nblk + blockIdx.x] = cnt[t];
}

__global__ __launch_bounds__(256) void k_scan_block2(int* __restrict__ g,
                                                     int* __restrict__ bsum, int L) {
    __shared__ int s[256];
    const int t = threadIdx.x;
    const int i = blockIdx.x * 256 + t;
    const int v = (i < L) ? g[i] : 0;
    s[t] = v;
    __syncthreads();
    for (int off = 1; off < 256; off <<= 1) {
        const int tv = (t >= off) ? s[t - off] : 0;
        __syncthreads();
        s[t] += tv;
        __syncthreads();
    }
    if (i < L) g[i] = s[t] - v;
    if (t == 255) bsum[blockIdx.x] = s[255];
}

__global__ __launch_bounds__(1024) void k_scan_sums(int* __restrict__ bsum, int NB) {
    __shared__ int s[1024];
    const int t = threadIdx.x;
    const int v = (t < NB) ? bsum[t] : 0;
    s[t] = v;
    __syncthreads();
    for (int off = 1; off < 1024; off <<= 1) {
        const int tv = (t >= off) ? s[t - off] : 0;
        __syncthreads();
        s[t] += tv;
        __syncthreads();
    }
    if (t < NB) bsum[t] = s[t] - v;
}

__global__ __launch_bounds__(256) void k_scan_add2(int* __restrict__ g,
                                                   const int* __restrict__ bsum, int L) {
    const int i = blockIdx.x * 256 + threadIdx.x;
    if (i < L) g[i] += bsum[blockIdx.x];
}

__global__ __launch_bounds__(256) void k_bucket_scatter(const int* __restrict__ ei,
                                                        const int* __restrict__ gbase,
                                                        int2* __restrict__ buf2,
                                                        int E, int nblk, int nbkt) {
    __shared__ int cnt[256];
    __shared__ int sbase[256];
    const int t = threadIdx.x;
    cnt[t] = 0;
    if (t < nbkt) sbase[t] = gbase[t * nblk + blockIdx.x];
    __syncthreads();
    const int base = blockIdx.x * 4096;
#pragma unroll
    for (int i = 0; i < 16; ++i) {
        const int e = base + i * 256 + t;
        if (e < E) {
            const int src = ei[e];
            const int dst = ei[E + e];
            const int b = dst >> 9;
            const int r = atomicAdd(&cnt[b], 1);
            buf2[sbase[b] + r] = make_int2(src, dst);
        }
    }
}

__global__ __launch_bounds__(256) void k_bucket_csr(const int2* __restrict__ buf2,
                                                    const int* __restrict__ gbase,
                                                    int* __restrict__ rowptr,
                                                    int* __restrict__ esrc,
                                                    int* __restrict__ sdst,
                                                    int N, int E, int nblk, int nbkt) {
    __shared__ int hist[512], curs[512], ps[256];
    __shared__ int sh_base, sh_end;
    const int t = threadIdx.x;
    const int b = blockIdx.x;
    const int node0 = b << 9;
    if (t == 0) {
        sh_base = gbase[b * nblk];
        sh_end  = (b + 1 < nbkt) ? gbase[(b + 1) * nblk] : E;
        if (b == 0) rowptr[N] = E;
    }
    hist[t] = 0;
    hist[t + 256] = 0;
    __syncthreads();
    const int eb = sh_base, ee = sh_end;
    for (int e = eb + t; e < ee; e += 256)
        atomicAdd(&hist[buf2[e].y - node0], 1);
    __syncthreads();
    const int p0 = hist[2 * t], p1 = hist[2 * t + 1];
    const int pr = p0 + p1;
    ps[t] = pr;
    __syncthreads();
    for (int off = 1; off < 256; off <<= 1) {
        const int v = (t >= off) ? ps[t - off] : 0;
        __syncthreads();
        ps[t] += v;
        __syncthreads();
    }
    const int e0 = ps[t] - pr;
    curs[2 * t]     = e0;
    curs[2 * t + 1] = e0 + p0;
    const int nn = min(512, N - node0);
    if (2 * t < nn)     rowptr[node0 + 2 * t]     = eb + e0;
    if (2 * t + 1 < nn) rowptr[node0 + 2 * t + 1] = eb + e0 + p0;
    __syncthreads();
    for (int e = eb + t; e < ee; e += 256) {
        const int2 r = buf2[e];
        const int rk = atomicAdd(&curs[r.y - node0], 1);
        esrc[eb + rk] = r.x;
        sdst[eb + rk] = r.y;
    }
}

// ---------------- legacy CSR build (fallback path only) ----------------
__global__ __launch_bounds__(256) void k_hist(const int* __restrict__ ei,
                                              int* __restrict__ deg, int E) {
    const int e = blockIdx.x * 256 + threadIdx.x;
    if (e < E) atomicAdd(&deg[ei[E + e]], 1);
}

__global__ __launch_bounds__(256) void k_scan_block(const int* __restrict__ deg,
                                                    int* __restrict__ rowptr,
                                                    int* __restrict__ bsum, int N) {
    __shared__ int s[256];
    const int t = threadIdx.x;
    const int i = blockIdx.x * 256 + t;
    const int v = (i < N) ? deg[i] : 0;
    s[t] = v;
    __syncthreads();
    for (int off = 1; off < 256; off <<= 1) {
        const int tv = (t >= off) ? s[t - off] : 0;
        __syncthreads();
        s[t] += tv;
        __syncthreads();
    }
    if (i < N) rowptr[i] = s[t] - v;
    if (t == 255) bsum[blockIdx.x] = s[255];
}

__global__ __launch_bounds__(256) void k_scan_add(int* __restrict__ rowptr,
                                                  const int* __restrict__ bsum,
                                                  int* __restrict__ cursor, int N, int E) {
    const int i = blockIdx.x * 256 + threadIdx.x;
    if (i < N) {
        const int r = rowptr[i] + bsum[blockIdx.x];
        rowptr[i] = r;
        cursor[i] = r;
    }
    if (i == 0) rowptr[N] = E;
}

__global__ __launch_bounds__(256) void k_scatter(const int* __restrict__ ei,
                                                 int* __restrict__ cursor,
                                                 int* __restrict__ esrc, int E) {
    const int e = blockIdx.x * 256 + threadIdx.x;
    if (e >= E) return;
    const int src = ei[e];
    const int dst = ei[E + e];
    const int pos = atomicAdd(&cursor[dst], 1);
    esrc[pos] = src;
}

// ---------------- W prep: wt[c][k] = (half) W[k][c]  (K=128, C=256) --------
__global__ __launch_bounds__(256) void k_prep_w(const float* __restrict__ W,
                                                __half* __restrict__ wt, int K, int C) {
    const int i = blockIdx.x * 256 + threadIdx.x;
    if (i >= K * C) return;
    const int c = i % C;   // coalesced read across c
    const int k = i / C;
    wt[(size_t)c * K + k] = __float2half(W[(size_t)k * C + c]);
}

// ---------------- layer-1 GEMM via MFMA fp16 ----------------
// x[N,128] @ W1[128,256] -> h fp16 [N][ (c%32)*8 + c/32 ].
// Block: 32 rows, 4 waves; wave w: row-group rg=w>>1 (16 rows), col-tiles
// ct0=(w&1)*8 .. +7 (16 cols each). K chunks of 32.
// A/B fragment slot j, group g=lane>>4 mapped to k = kc + g*8 + j for BOTH
// operands (bijection -> correct regardless of HW internal k order).
__global__ __launch_bounds__(256) void k_gemm_mfma1(const float* __restrict__ x,
                                                    const __half* __restrict__ wt, // [256][128]
                                                    __half* __restrict__ h, int N) {
    constexpr int PADX = 136;  // halves per xs row (128 + 8)
    constexpr int WTS  = 40;   // halves per wbuf row (32 + 8)
    constexpr int HSS  = 264;  // halves per hs row (256 + 8)
    __shared__ __align__(16) __half xs16[32 * PADX];
    __shared__ __align__(16) __half wbuf[256 * WTS];   // 10240 halves; aliased as hs (32*264=8448)
    __half* hs = wbuf;

    const int t    = threadIdx.x;
    const int n0   = blockIdx.x * 32;
    const int lane = t & 63;
    const int w    = t >> 6;
    const int rg   = w >> 1;
    const int ct0  = (w & 1) * 8;
    const int lr   = lane & 15;
    const int g    = lane >> 4;

    // stage x -> fp16 LDS (32 rows x 128)
    for (int p = 0; p < 4; ++p) {
        const int idx = p * 256 + t;
        const int row = idx >> 5;
        const int q   = idx & 31;
        float4 v = make_float4(0.f, 0.f, 0.f, 0.f);
        if (n0 + row < N) v = *(const float4*)(x + (size_t)(n0 + row) * 128 + q * 4);
        __half2* dst = (__half2*)(xs16 + row * PADX + q * 4);
        dst[0] = __floats2half2_rn(v.x, v.y);
        dst[1] = __floats2half2_rn(v.z, v.w);
    }

    f32x4 acc[8];
#pragma unroll
    for (int j = 0; j < 8; ++j) acc[j] = (f32x4){0.f, 0.f, 0.f, 0.f};

#pragma unroll 1
    for (int kc = 0; kc < 128; kc += 32) {
        __syncthreads();
        // stage W chunk: wbuf[c][0..31] = wt[c][kc..kc+31]
        for (int p = 0; p < 4; ++p) {
            const int idx  = p * 256 + t;
            const int c    = idx >> 2;
            const int part = idx & 3;
            const f16x8 vv = *(const f16x8*)(wt + (size_t)c * 128 + kc + part * 8);
            *(f16x8*)(wbuf + c * WTS + part * 8) = vv;
        }
        __syncthreads();
        const f16x8 a = *(const f16x8*)(xs16 + (rg * 16 + lr) * PADX + kc + g * 8);
#pragma unroll
        for (int j = 0; j < 8; ++j) {
            const f16x8 b = *(const f16x8*)(wbuf + ((ct0 + j) * 16 + lr) * WTS + g * 8);
            acc[j] = __builtin_amdgcn_mfma_f32_16x16x32_f16(a, b, acc[j], 0, 0, 0);
        }
    }

    __syncthreads();   // wbuf -> hs reuse
    // scatter D frags into hs with the [f*8+head] layout
#pragma unroll
    for (int j = 0; j < 8; ++j) {
        const int c   = (ct0 + j) * 16 + lr;
        const int idx = (c & 31) * 8 + (c >> 5);
#pragma unroll
        for (int r = 0; r < 4; ++r) {
            const int row = rg * 16 + g * 4 + r;
            hs[row * HSS + idx] = __float2half(acc[j][r]);
        }
    }
    __syncthreads();
    // coalesced copy hs -> h
    for (int p = 0; p < 4; ++p) {
        const int idx = p * 256 + t;
        const int row = idx >> 5;
        const int q   = idx & 31;
        if (n0 + row < N) {
            const f16x8 vv = *(const f16x8*)(hs + row * HSS + q * 8);
            *(f16x8*)(h + (size_t)(n0 + row) * 256 + q * 8) = vv;
        }
    }
}

// ---------------- layer-2 GEMM: 4x8 register tile, W in LDS (KC=16) --------
template <int IN, int C, int F>
__global__ __launch_bounds__(256) void k_gemm_big(const float* __restrict__ x,
                                                  const float* __restrict__ W,
                                                  __half* __restrict__ h, int N) {
    constexpr int CJ = C / 32;
    constexpr int KC = 16;
    __shared__ float xs[32 * IN];
    __shared__ float wlds[KC * (C + 4)];
    const int t  = threadIdx.x;
    const int n0 = blockIdx.x * 32;

    const float4* src4 = (const float4*)(x + (size_t)n0 * IN);
    float4* xs4 = (float4*)xs;
    constexpr int NV = 32 * IN / 4;
    for (int idx = t; idx < NV; idx += 256) {
        const int row = idx / (IN / 4);
        xs4[idx] = (n0 + row < N) ? src4[idx] : make_float4(0.f, 0.f, 0.f, 0.f);
    }

    const int tc = t & 31;
    const int tr = t >> 5;
    float acc[4][CJ];
#pragma unroll
    for (int i = 0; i < 4; ++i)
#pragma unroll
        for (int j = 0; j < CJ; ++j) acc[i][j] = 0.f;

#pragma unroll 1
    for (int kc = 0; kc < IN; kc += KC) {
        __syncthreads();
        for (int idx = t; idx < KC * C; idx += 256) {
            const int k = idx / C, c = idx % C;
            wlds[k * (C + 4) + c] = W[(size_t)(kc + k) * C + c];
        }
        __syncthreads();
#pragma unroll 1
        for (int q = 0; q < KC / 4; ++q) {
            float4 xv[4];
#pragma unroll
            for (int i = 0; i < 4; ++i)
                xv[i] = *(const float4*)&xs[(tr * 4 + i) * IN + kc + q * 4];
#pragma unroll
            for (int kk = 0; kk < 4; ++kk) {
                float wv[CJ];
#pragma unroll
                for (int j = 0; j < CJ; ++j)
                    wv[j] = wlds[(q * 4 + kk) * (C + 4) + tc + j * 32];
#pragma unroll
                for (int i = 0; i < 4; ++i) {
                    const float xvv = ((const float*)&xv[i])[kk];
#pragma unroll
                    for (int j = 0; j < CJ; ++j)
                        acc[i][j] = fmaf(xvv, wv[j], acc[i][j]);
                }
            }
        }
    }

#pragma unroll
    for (int i = 0; i < 4; ++i) {
        const int r = n0 + tr * 4 + i;
        if (r < N) {
#pragma unroll
            for (int j = 0; j < CJ; ++j) {
                const int c = tc + j * 32;
                h[(size_t)r * C + (c % F) * 8 + (c / F)] = __float2half(acc[i][j]);
            }
        }
    }
}

// Attention dots from fp16 h [N, F, HG]; writes a_s/a_d [N,8] at head hb+hl.
template <int F, int HG>
__global__ __launch_bounds__(256) void k_dots_h(const __half* __restrict__ h,
                                                const float* __restrict__ atts,
                                                const float* __restrict__ attd,
                                                float* __restrict__ as_,
                                                float* __restrict__ ad_, int N, int hb) {
    const int i = blockIdx.x * 256 + threadIdx.x;
    if (i >= N * HG) return;
    const int n  = i / HG;
    const int hl = i % HG;
    const int hg = hb + hl;
    const __half* hp = h + (size_t)n * (F * HG) + hl;
    const float* sv = atts + hg * F;
    const float* dv = attd + hg * F;
    float s = 0.f, d = 0.f;
#pragma unroll
    for (int f = 0; f < F; ++f) {
        const float v = __half2float(hp[f * HG]);
        s = fmaf(v, sv[f], s);
        d = fmaf(v, dv[f], d);
    }
    as_[(size_t)n * 8 + hg] = s;
    ad_[(size_t)n * 8 + hg] = d;
}

// Slot-parallel alpha: coalesced esrc/sdst reads, L2 gathers, coalesced store.
__global__ __launch_bounds__(256) void k_alpha_csr(const int* __restrict__ esrc,
                                                   const int* __restrict__ sdst,
                                                   const float* __restrict__ as_,
                                                   const float* __restrict__ ad_,
                                                   __half* __restrict__ exbuf, int E) {
    const int p = blockIdx.x * 256 + threadIdx.x;
    if (p >= E) return;
    const int src = esrc[p];
    const int dst = sdst[p];
    const float4 s0 = *(const float4*)(as_ + (size_t)src * 8);
    const float4 s1 = *(const float4*)(as_ + (size_t)src * 8 + 4);
    const float4 d0 = *(const float4*)(ad_ + (size_t)dst * 8);
    const float4 d1 = *(const float4*)(ad_ + (size_t)dst * 8 + 4);
    __half tmp[8];
    tmp[0] = __float2half(lrelu_exp(s0.x + d0.x));
    tmp[1] = __float2half(lrelu_exp(s0.y + d0.y));
    tmp[2] = __float2half(lrelu_exp(s0.z + d0.z));
    tmp[3] = __float2half(lrelu_exp(s0.w + d0.w));
    tmp[4] = __float2half(lrelu_exp(s1.x + d1.x));
    tmp[5] = __float2half(lrelu_exp(s1.y + d1.y));
    tmp[6] = __float2half(lrelu_exp(s1.z + d1.z));
    tmp[7] = __float2half(lrelu_exp(s1.w + d1.w));
    *(float4*)(exbuf + (size_t)p * 8) = *(const float4*)tmp;
}

// Per-(node,head) denominator from CONTIGUOUS exbuf CSR rows.
__global__ __launch_bounds__(256) void k_rinv(const int* __restrict__ rowptr,
                                              const __half* __restrict__ exbuf,
                                              float* __restrict__ rinv, int N) {
    const int i = blockIdx.x * 256 + threadIdx.x;
    if (i >= N * 8) return;
    const int n  = i >> 3;
    const int hh = i & 7;
    const int r0 = rowptr[n], r1 = rowptr[n + 1];
    float den = 0.f;
    for (int e = r0; e < r1; ++e)
        den += __half2float(exbuf[(size_t)e * 8 + hh]);
    rinv[i] = 1.f / (den + 1e-16f);
}

// Aggregation: 2-way edge unroll, dual accumulators, rinv applied at end.
template <int F, int MODE>
__global__ __launch_bounds__(256) void k_agg_ex3(const int* __restrict__ rowptr,
                                                 const int* __restrict__ esrc,
                                                 const __half* __restrict__ exbuf,
                                                 const float* __restrict__ rinv,
                                                 const __half* __restrict__ h,
                                                 const float* __restrict__ bias,
                                                 float* __restrict__ outp, int N) {
    constexpr int NPB = 256 / F;
    const int n = blockIdx.x * NPB + threadIdx.x / F;
    const int f = threadIdx.x % F;
    if (n >= N) return;
    const int r0 = rowptr[n], r1 = rowptr[n + 1];

    float accA[8], accB[8];
#pragma unroll
    for (int k = 0; k < 8; ++k) { accA[k] = 0.f; accB[k] = 0.f; }

    int e = r0;
    for (; e + 2 <= r1; e += 2) {
        const int s0 = esrc[e];
        const int s1 = esrc[e + 1];
        const float4 ex0 = *(const float4*)(exbuf + (size_t)e * 8);
        const float4 ex1 = *(const float4*)(exbuf + (size_t)(e + 1) * 8);
        const float4 h0  = *(const float4*)(h + (size_t)s0 * (F * 8) + f * 8);
        const float4 h1  = *(const float4*)(h + (size_t)s1 * (F * 8) + f * 8);
        const __half2* e20 = (const __half2*)&ex0;
        const __half2* h20 = (const __half2*)&h0;
        const __half2* e21 = (const __half2*)&ex1;
        const __half2* h21 = (const __half2*)&h1;
#pragma unroll
        for (int k = 0; k < 4; ++k) {
            const float2 ef0 = __half22float2(e20[k]);
            const float2 hf0 = __half22float2(h20[k]);
            accA[2 * k]     = fmaf(ef0.x, hf0.x, accA[2 * k]);
            accA[2 * k + 1] = fmaf(ef0.y, hf0.y, accA[2 * k + 1]);
            const float2 ef1 = __half22float2(e21[k]);
            const float2 hf1 = __half22float2(h21[k]);
            accB[2 * k]     = fmaf(ef1.x, hf1.x, accB[2 * k]);
            accB[2 * k + 1] = fmaf(ef1.y, hf1.y, accB[2 * k + 1]);
        }
    }
    if (e < r1) {
        const int s0 = esrc[e];
        const float4 ex0 = *(const float4*)(exbuf + (size_t)e * 8);
        const float4 h0  = *(const float4*)(h + (size_t)s0 * (F * 8) + f * 8);
        const __half2* e20 = (const __half2*)&ex0;
        const __half2* h20 = (const __half2*)&h0;
#pragma unroll
        for (int k = 0; k < 4; ++k) {
            const float2 ef0 = __half22float2(e20[k]);
            const float2 hf0 = __half22float2(h20[k]);
            accA[2 * k]     = fmaf(ef0.x, hf0.x, accA[2 * k]);
            accA[2 * k + 1] = fmaf(ef0.y, hf0.y, accA[2 * k + 1]);
        }
    }
    const float* rv = rinv + (size_t)n * 8;
    float s = 0.f;
#pragma unroll
    for (int k = 0; k < 8; ++k) s += (accA[k] + accB[k]) * rv[k];
    float v = 0.125f * s + bias[f];
    if constexpr (MODE == 1) v = v > 0.f ? v : 0.f;
    outp[(size_t)n * F + f] = v;
}

// ---------------- fallback path (r8-proven) ----------------
template <int IN, int C, int OW, int F>
__global__ __launch_bounds__(256) void k_gemm_h(const float* __restrict__ x,
                                                const float* __restrict__ W,
                                                __half* __restrict__ h, int N, int c0) {
    constexpr int HG = C / F;
    __shared__ float xs[32 * IN];
    const int t  = threadIdx.x;
    const int n0 = blockIdx.x * 32;
    const float4* src4 = (const float4*)(x + (size_t)n0 * IN);
    float4* xs4 = (float4*)xs;
    constexpr int NV = 32 * IN / 4;
    for (int idx = t; idx < NV; idx += 256) {
        const int row = idx / (IN / 4);
        xs4[idx] = (n0 + row < N) ? src4[idx] : make_float4(0.f, 0.f, 0.f, 0.f);
    }
    __syncthreads();
    const int idx = t % C;
    const int r0  = t / C;
    constexpr int RSTEP = 256 / C;
    constexpr int RPT   = 32 / RSTEP;
    const int f  = idx / HG;
    const int hd = idx % HG;
    float acc[RPT];
#pragma unroll
    for (int i = 0; i < RPT; ++i) acc[i] = 0.f;
    const float* Wc = W + c0 + hd * F + f;
#pragma unroll 1
    for (int k = 0; k < IN; k += 4) {
        const float w0 = Wc[(k + 0) * OW];
        const float w1 = Wc[(k + 1) * OW];
        const float w2 = Wc[(k + 2) * OW];
        const float w3 = Wc[(k + 3) * OW];
#pragma unroll
        for (int i = 0; i < RPT; ++i) {
            const int r = r0 + i * RSTEP;
            const float4 xv = *(const float4*)&xs[r * IN + k];
            acc[i] = fmaf(xv.x, w0, fmaf(xv.y, w1, fmaf(xv.z, w2, fmaf(xv.w, w3, acc[i]))));
        }
    }
#pragma unroll
    for (int i = 0; i < RPT; ++i) {
        const int r = r0 + i * RSTEP;
        if (n0 + r < N) h[(size_t)(n0 + r) * C + idx] = __float2half(acc[i]);
    }
}

template <int HG>
__global__ __launch_bounds__(256) void k_denom(const int* __restrict__ rowptr,
                                               const int* __restrict__ esrc,
                                               const float* __restrict__ as_,
                                               const float* __restrict__ ad_,
                                               float* __restrict__ rinv, int N, int hb) {
    const int i = blockIdx.x * 256 + threadIdx.x;
    if (i >= N * HG) return;
    const int n  = i / HG;
    const int hl = i % HG;
    const float ad = ad_[(size_t)n * 8 + hb + hl];
    const int r0 = rowptr[n];
    const int r1 = rowptr[n + 1];
    float s = 0.f;
    for (int e = r0; e < r1; ++e)
        s += lrelu_exp(as_[(size_t)esrc[e] * 8 + hb + hl] + ad);
    rinv[(size_t)n * 8 + hb + hl] = 1.f / (s + 1e-16f);
}

template <int F, int HG>
__global__ __launch_bounds__(256) void k_csr_agg_hg(const int* __restrict__ rowptr,
                                                    const int* __restrict__ esrc,
                                                    const float* __restrict__ as_,
                                                    const float* __restrict__ ad_,
                                                    const float* __restrict__ rinv,
                                                    const __half* __restrict__ h,
                                                    float* __restrict__ outp,
                                                    int N, int hb) {
    constexpr int NPB = 256 / F;
    const int n = blockIdx.x * NPB + threadIdx.x / F;
    const int f = threadIdx.x % F;
    if (n >= N) return;
    const int r0 = rowptr[n];
    const int r1 = rowptr[n + 1];
    float ad[HG], rv[HG];
#pragma unroll
    for (int k = 0; k < HG; ++k) {
        ad[k] = ad_[(size_t)n * 8 + hb + k];
        rv[k] = rinv[(size_t)n * 8 + hb + k];
    }
    float a0 = 0.f;
    for (int e = r0; e < r1; ++e) {
        const int src = esrc[e];
        const float* sp = as_ + (size_t)src * 8 + hb;
        const __half* hp = h + (size_t)src * (F * HG) + f * HG;
#pragma unroll
        for (int k = 0; k < HG; ++k) {
            const float al = lrelu_exp(sp[k] + ad[k]) * rv[k];
            a0 = fmaf(al, __half2float(hp[k]), a0);
        }
    }
    outp[(size_t)n * F + f] += 0.125f * a0;
}

__global__ __launch_bounds__(256) void k_relu_bias(float* __restrict__ a,
                                                   const float* __restrict__ b, int total) {
    const int i = blockIdx.x * 256 + threadIdx.x;
    if (i < total) {
        const float v = a[i] + b[i & 31];
        a[i] = v > 0.f ? v : 0.f;
    }
}

__global__ __launch_bounds__(256) void k_bias_inplace(float* __restrict__ a,
                                                      const float* __restrict__ b, int total) {
    const int i = blockIdx.x * 256 + threadIdx.x;
    if (i < total) a[i] += b[i & 15];
}

// ---------------- drivers ----------------
static void run_full(const float* x, const int* ei,
                     const float* W1, const float* as1, const float* ad1, const float* b1,
                     const float* W2, const float* as2, const float* ad2, const float* b2,
                     float* out, int N, int E, char* ws, hipStream_t stream) {
    auto align256 = [](size_t b) { return (b + 255) & ~(size_t)255; };
    size_t off = 0;
    auto alloc = [&](size_t bytes) { char* p = ws + off; off += align256(bytes); return p; };

    const int NBLKC = (E + 4095) / 4096;
    const int nbkt  = (N + 511) >> 9;
    const int L     = nbkt * NBLKC;

    __half* hbuf  = (__half*)alloc((size_t)N * 256 * 2);
    __half* exbuf = (__half*)alloc((size_t)E * 8 * 2);
    __half* wt16  = (__half*)alloc((size_t)256 * 128 * 2);
    float* a_s    = (float*)alloc((size_t)N * 8 * 4);
    float* a_d    = (float*)alloc((size_t)N * 8 * 4);
    float* rinv   = (float*)alloc((size_t)N * 8 * 4);
    size_t acc_bytes = (size_t)N * 32 * 4;
    size_t buf2_bytes = (size_t)E * 8;
    float* acc1   = (float*)alloc(acc_bytes > buf2_bytes ? acc_bytes : buf2_bytes);
    int2* buf2    = (int2*)acc1;            // aliased: buf2 dead before agg1 writes acc1
    int* rowptr   = (int*)alloc((size_t)(N + 1) * 4);
    int* esrc     = (int*)alloc((size_t)E * 4);
    int* sdst     = (int*)alloc((size_t)E * 4);
    int* gcnt     = (int*)alloc((size_t)L * 4);
    int* bsum2    = (int*)alloc(1024 * 4);

    // ---- bucket-sort CSR build ----
    const int NBs = (L + 255) / 256;
    k_bhist<<<NBLKC, 256, 0, stream>>>(ei, gcnt, E, NBLKC, nbkt);
    k_scan_block2<<<NBs, 256, 0, stream>>>(gcnt, bsum2, L);
    k_scan_sums<<<1, 1024, 0, stream>>>(bsum2, NBs);
    k_scan_add2<<<NBs, 256, 0, stream>>>(gcnt, bsum2, L);
    k_bucket_scatter<<<NBLKC, 256, 0, stream>>>(ei, gcnt, buf2, E, NBLKC, nbkt);
    k_bucket_csr<<<nbkt, 256, 0, stream>>>(buf2, gcnt, rowptr, esrc, sdst, N, E, NBLKC, nbkt);

    const int NBg = (N + 31) / 32;
    const int nbp = (N * 8 + 255) / 256;
    const int NBe = (E + 255) / 256;
    // layer 1 (MFMA fp16 GEMM)
    k_prep_w<<<(128 * 256 + 255) / 256, 256, 0, stream>>>(W1, wt16, 128, 256);
    k_gemm_mfma1<<<NBg, 256, 0, stream>>>(x, wt16, hbuf, N);
    k_dots_h<32, 8><<<nbp, 256, 0, stream>>>(hbuf, as1, ad1, a_s, a_d, N, 0);
    k_alpha_csr<<<NBe, 256, 0, stream>>>(esrc, sdst, a_s, a_d, exbuf, E);
    k_rinv<<<nbp, 256, 0, stream>>>(rowptr, exbuf, rinv, N);
    k_agg_ex3<32, 1><<<(N + 7) / 8, 256, 0, stream>>>(rowptr, esrc, exbuf, rinv, hbuf, b1, acc1, N);
    // layer 2 (exact fp32 GEMM)
    k_gemm_big<32, 128, 16><<<NBg, 256, 0, stream>>>(acc1, W2, hbuf, N);
    k_dots_h<16, 8><<<nbp, 256, 0, stream>>>(hbuf, as2, ad2, a_s, a_d, N, 0);
    k_alpha_csr<<<NBe, 256, 0, stream>>>(esrc, sdst, a_s, a_d, exbuf, E);
    k_rinv<<<nbp, 256, 0, stream>>>(rowptr, exbuf, rinv, N);
    k_agg_ex3<16, 2><<<(N + 15) / 16, 256, 0, stream>>>(rowptr, esrc, exbuf, rinv, hbuf, b2, out, N);
}

static void run_fallback4(const float* x, const int* ei,
                          const float* W1, const float* as1, const float* ad1, const float* b1,
                          const float* W2, const float* as2, const float* ad2, const float* b2,
                          float* out, int N, int E, char* ws, hipStream_t stream) {
    constexpr int HG = 4;
    auto align256 = [](size_t b) { return (b + 255) & ~(size_t)255; };
    size_t off = 0;
    auto alloc = [&](size_t bytes) { char* p = ws + off; off += align256(bytes); return p; };

    __half* hbuf = (__half*)alloc((size_t)N * HG * 32 * 2);
    float* a_s   = (float*)alloc((size_t)N * 8 * 4);
    float* a_d   = (float*)alloc((size_t)N * 8 * 4);
    float* rinv  = (float*)alloc((size_t)N * 8 * 4);
    float* acc1  = (float*)alloc((size_t)N * 32 * 4);
    int* rowptr  = (int*)alloc((size_t)(N + 1) * 4);
    int* cursor  = (int*)alloc((size_t)N * 4);
    int* deg     = (int*)alloc((size_t)N * 4);
    int* bsum    = (int*)alloc(1024 * 4);
    int* esrc    = (int*)alloc((size_t)E * 4);

    const int NBn = (N + 255) / 256;
    const int NBe = (E + 255) / 256;
    k_zero_int<<<512, 256, 0, stream>>>(deg, N);
    k_hist<<<NBe, 256, 0, stream>>>(ei, deg, E);
    k_scan_block<<<NBn, 256, 0, stream>>>(deg, rowptr, bsum, N);
    k_scan_sums<<<1, 1024, 0, stream>>>(bsum, NBn);
    k_scan_add<<<NBn, 256, 0, stream>>>(rowptr, bsum, cursor, N, E);
    k_scatter<<<NBe, 256, 0, stream>>>(ei, cursor, esrc, E);

    k_zero<<<512, 256, 0, stream>>>(acc1, N * 32);
    k_zero<<<512, 256, 0, stream>>>(out, N * 16);

    const int nbp = (N * HG + 255) / 256;
    for (int g = 0; g < 2; ++g) {
        k_gemm_h<128, 128, 256, 32><<<NBn * 8, 256, 0, stream>>>(x, W1, hbuf, N, g * 128);
        k_dots_h<32, HG><<<nbp, 256, 0, stream>>>(hbuf, as1, ad1, a_s, a_d, N, g * HG);
        k_denom<HG><<<nbp, 256, 0, stream>>>(rowptr, esrc, a_s, a_d, rinv, N, g * HG);
        k_csr_agg_hg<32, HG><<<(N + 7) / 8, 256, 0, stream>>>(rowptr, esrc, a_s, a_d, rinv,
                                                              hbuf, acc1, N, g * HG);
    }
    k_relu_bias<<<(N * 32 + 255) / 256, 256, 0, stream>>>(acc1, b1, N * 32);

    for (int g = 0; g < 2; ++g) {
        k_gemm_h<32, 64, 128, 16><<<NBn * 8, 256, 0, stream>>>(acc1, W2, hbuf, N, g * 64);
        k_dots_h<16, HG><<<nbp, 256, 0, stream>>>(hbuf, as2, ad2, a_s, a_d, N, g * HG);
        k_denom<HG><<<nbp, 256, 0, stream>>>(rowptr, esrc, a_s, a_d, rinv, N, g * HG);
        k_csr_agg_hg<16, HG><<<(N + 15) / 16, 256, 0, stream>>>(rowptr, esrc, a_s, a_d, rinv,
                                                                hbuf, out, N, g * HG);
    }
    k_bias_inplace<<<(N * 16 + 255) / 256, 256, 0, stream>>>(out, b2, N * 16);
}

extern "C" void kernel_launch(void* const* d_in, const int* in_sizes, int n_in,
                              void* d_out, int out_size, void* d_ws, size_t ws_size,
                              hipStream_t stream) {
    const float* x   = (const float*)d_in[0];
    const int*   ei  = (const int*)d_in[1];
    const float* W1  = (const float*)d_in[2];
    const float* as1 = (const float*)d_in[3];
    const float* ad1 = (const float*)d_in[4];
    const float* b1  = (const float*)d_in[5];
    const float* W2  = (const float*)d_in[6];
    const float* as2 = (const float*)d_in[7];
    const float* ad2 = (const float*)d_in[8];
    const float* b2  = (const float*)d_in[9];
    float* out = (float*)d_out;

    const int N = in_sizes[0] / 128;
    const int E = in_sizes[1] / 2;

    const int NBLKC = (E + 4095) / 4096;
    const int nbkt  = (N + 511) >> 9;
    const int L     = nbkt * NBLKC;
    const size_t acc_or_buf2 = ((size_t)N * 32 * 4 > (size_t)E * 8) ? (size_t)N * 32 * 4
                                                                    : (size_t)E * 8;
    const size_t need_full = (size_t)2 * N * 256 + (size_t)2 * E * 8 +
                             (size_t)2 * 256 * 128 +
                             (size_t)4 * N * 24 + acc_or_buf2 +
                             (size_t)4 * (N + 1) + (size_t)8 * E +
                             (size_t)4 * L + 4096 + 24 * 256;
    char* ws = (char*)d_ws;
    if (ws_size >= need_full && nbkt <= 256 && (L + 255) / 256 <= 1024) {
        run_full(x, ei, W1, as1, ad1, b1, W2, as2, ad2, b2, out, N, E, ws, stream);
    } else {
        run_fallback4(x, ei, W1, as1, ad1, b1, W2, as2, ad2, b2, out, N, E, ws, stream);
    }
}